// Round 12
// baseline (212.097 us; speedup 1.0000x reference)
//
#include <hip/hip_runtime.h>
#include <hip/hip_bf16.h>

#define B_  2
#define S_  2048
#define D_  1024
#define H_  16
#define DK_ 64
#define M_  (B_ * S_)   // 4096

typedef short short8 __attribute__((ext_vector_type(8)));
typedef float float4v __attribute__((ext_vector_type(4)));

// log2(e)/8 : folded into Q at projection so attention exp is a bare v_exp_f32
#define QSCALE 0.18033688011112042f

static __device__ __forceinline__ ushort f32_to_bf16bits(float f) {
    union { __hip_bfloat16 h; ushort u; } cv;
    cv.h = __float2bfloat16(f);
    return cv.u;
}

// async global->LDS, 16B per lane (lands at wave-uniform base + lane*16)
static __device__ __forceinline__ void glds16(const ushort* g, ushort* l) {
    __builtin_amdgcn_global_load_lds(
        (const __attribute__((address_space(1))) unsigned int*)g,
        (__attribute__((address_space(3))) unsigned int*)l, 16, 0, 0);
}

// ---------------------------------------------------------------------------
// prep: z in [0,3) -> transpose+convert W_z[k][n] fp32 -> Wt[n][k] bf16
//       z in [3,11) -> convert X fp32 -> bf16
// ---------------------------------------------------------------------------
__global__ __launch_bounds__(256) void prep(
    const float* __restrict__ X, const float* __restrict__ W0,
    const float* __restrict__ W1, const float* __restrict__ W2,
    ushort* __restrict__ Xb, ushort* __restrict__ Wt)
{
    const int z = blockIdx.z;
    const int t = threadIdx.x;

    if (z >= 3) {   // convert X
        const int blk = (z - 3) * 256 + blockIdx.y * 16 + blockIdx.x;
        const int i = blk * 2048 + t * 8;
        float4v a = *(const float4v*)(X + i);
        float4v b = *(const float4v*)(X + i + 4);
        short8 o;
        o[0] = (short)f32_to_bf16bits(a[0]); o[1] = (short)f32_to_bf16bits(a[1]);
        o[2] = (short)f32_to_bf16bits(a[2]); o[3] = (short)f32_to_bf16bits(a[3]);
        o[4] = (short)f32_to_bf16bits(b[0]); o[5] = (short)f32_to_bf16bits(b[1]);
        o[6] = (short)f32_to_bf16bits(b[2]); o[7] = (short)f32_to_bf16bits(b[3]);
        *(short8*)(Xb + i) = o;
        return;
    }

    const float* W = (z == 0) ? W0 : ((z == 1) ? W1 : W2);
    ushort* out = Wt + (size_t)z * D_ * D_;

    __shared__ ushort tile[64 * 72];
    int n0 = blockIdx.x * 64, k0 = blockIdx.y * 64;
    int r = t >> 3, g = t & 7;

    #pragma unroll
    for (int p = 0; p < 2; ++p) {
        int rr = r + p * 32;
        const float* src = W + (size_t)(k0 + rr) * D_ + n0 + g * 8;
        float4v a = *(const float4v*)src;
        float4v b = *(const float4v*)(src + 4);
        short8 o;
        o[0] = (short)f32_to_bf16bits(a[0]); o[1] = (short)f32_to_bf16bits(a[1]);
        o[2] = (short)f32_to_bf16bits(a[2]); o[3] = (short)f32_to_bf16bits(a[3]);
        o[4] = (short)f32_to_bf16bits(b[0]); o[5] = (short)f32_to_bf16bits(b[1]);
        o[6] = (short)f32_to_bf16bits(b[2]); o[7] = (short)f32_to_bf16bits(b[3]);
        *(short8*)&tile[rr * 72 + g * 8] = o;
    }
    __syncthreads();
    #pragma unroll
    for (int p = 0; p < 2; ++p) {
        int rr = r + p * 32;
        short8 v;
        #pragma unroll
        for (int i = 0; i < 8; ++i)
            v[i] = (short)tile[(g * 8 + i) * 72 + rr];
        *(short8*)(out + (size_t)(n0 + rr) * D_ + k0 + g * 8) = v;
    }
}

// ---------------------------------------------------------------------------
// FUSED-z QKV projection (round-7/8 best-known): one block = (m 64, n 128)
// computing q, k AND v.  A staged once, 48 MFMA per barrier pair; 56 KB LDS
// = 2 blocks/CU.  k/v skipped (block-uniform) beyond length[b].
// z==0 (Q) epilogue folds score-scale*log2(e) into the values.
// ---------------------------------------------------------------------------
__global__ __launch_bounds__(256, 2) void proj_gemm(
    const ushort* __restrict__ X,    // [4096][1024] bf16
    const ushort* __restrict__ Wt,   // [3][1024][1024] bf16, n-major
    const float* __restrict__ b0, const float* __restrict__ b1,
    const float* __restrict__ b2,
    const int* __restrict__ length,
    ushort* __restrict__ qkv)        // [3][4M] bf16
{
    const int m0 = blockIdx.x * 64, n0 = blockIdx.y * 128;
    const int bidx = m0 >> 11;
    const int s0 = m0 & (S_ - 1);
    const bool kv = (s0 < length[bidx]);   // block-uniform

    __shared__ __align__(16) ushort As[64 * 64];        //  8 KB
    __shared__ __align__(16) ushort Bs[3][128 * 64];    // 48 KB

    const int t = threadIdx.x;
    const int lane = t & 63, wid = t >> 6;
    const int quad = lane >> 4, l16 = lane & 15;
    const int wr = wid >> 1, wc = wid & 1;

    float4v accq[2][4] = {}, acck[2][4] = {}, accv[2][4] = {};

    for (int kt = 0; kt < 16; ++kt) {
        const int k0 = kt * 64;
        __syncthreads();
        #pragma unroll
        for (int j = 0; j < 2; ++j) {          // A: 512 chunks, 128/wave
            const int cid = wid * 128 + j * 64 + lane;
            const int row = cid >> 3;
            const int cl  = (cid & 7) ^ (row & 7);
            glds16(X + (size_t)(m0 + row) * D_ + k0 + cl * 8, &As[cid * 8]);
        }
        #pragma unroll
        for (int j = 0; j < 4; ++j) {          // B panels: 1024 chunks each
            const int cid = wid * 256 + j * 64 + lane;
            const int row = cid >> 3;
            const int cl  = (cid & 7) ^ (row & 7);
            const size_t off = (size_t)(n0 + row) * D_ + k0 + cl * 8;
            glds16(Wt + off, &Bs[0][cid * 8]);
            if (kv) {
                glds16(Wt + (size_t)D_ * D_ + off,     &Bs[1][cid * 8]);
                glds16(Wt + (size_t)2 * D_ * D_ + off, &Bs[2][cid * 8]);
            }
        }
        __syncthreads();

        #pragma unroll
        for (int ks = 0; ks < 2; ++ks) {
            short8 a[2];
            #pragma unroll
            for (int i = 0; i < 2; ++i) {
                const int r = wr * 32 + i * 16 + l16;
                const int ph = (ks * 4 + quad) ^ (r & 7);
                a[i] = *(short8*)&As[r * 64 + ph * 8];
            }
            short8 bq[4];
            #pragma unroll
            for (int j = 0; j < 4; ++j) {
                const int r = wc * 64 + j * 16 + l16;
                const int ph = (ks * 4 + quad) ^ (r & 7);
                bq[j] = *(short8*)&Bs[0][r * 64 + ph * 8];
            }
            #pragma unroll
            for (int i = 0; i < 2; ++i)
                #pragma unroll
                for (int j = 0; j < 4; ++j)
                    accq[i][j] = __builtin_amdgcn_mfma_f32_16x16x32_bf16(
                        a[i], bq[j], accq[i][j], 0, 0, 0);
            if (kv) {
                short8 bk[4], bv[4];
                #pragma unroll
                for (int j = 0; j < 4; ++j) {
                    const int r = wc * 64 + j * 16 + l16;
                    const int ph = (ks * 4 + quad) ^ (r & 7);
                    bk[j] = *(short8*)&Bs[1][r * 64 + ph * 8];
                    bv[j] = *(short8*)&Bs[2][r * 64 + ph * 8];
                }
                #pragma unroll
                for (int i = 0; i < 2; ++i)
                    #pragma unroll
                    for (int j = 0; j < 4; ++j) {
                        acck[i][j] = __builtin_amdgcn_mfma_f32_16x16x32_bf16(
                            a[i], bk[j], acck[i][j], 0, 0, 0);
                        accv[i][j] = __builtin_amdgcn_mfma_f32_16x16x32_bf16(
                            a[i], bv[j], accv[i][j], 0, 0, 0);
                    }
            }
        }
    }

    // epilogue: +bias, scatter into head layouts.
    #pragma unroll
    for (int j = 0; j < 4; ++j) {
        const int col = n0 + wc * 64 + j * 16 + l16;
        const int h = col >> 6, dk = col & (DK_ - 1);
        const float bvq = b0[col], bvk = b1[col], bvv = b2[col];
        #pragma unroll
        for (int i = 0; i < 2; ++i) {
            #pragma unroll
            for (int rr = 0; rr < 4; ++rr) {
                const int row = m0 + wr * 32 + i * 16 + quad * 4 + rr;
                const int s = row & (S_ - 1);
                const size_t hdr = ((size_t)(bidx * H_ + h) * S_ + s) * DK_ + dk;
                qkv[hdr] = f32_to_bf16bits((accq[i][j][rr] + bvq) * QSCALE);
                if (kv) {
                    qkv[(size_t)M_ * D_ + hdr] =
                        f32_to_bf16bits(acck[i][j][rr] + bvk);
                    qkv[(size_t)2 * M_ * D_ +
                        ((size_t)(bidx * H_ + h) * DK_ + dk) * S_ + s] =
                        f32_to_bf16bits(accv[i][j][rr] + bvv);
                }
            }
        }
    }
}

// ---------------------------------------------------------------------------
// attention, BARRIER-FREE: block = (b, h, 128 q), 4 waves x two 16-q strips.
// With DK=64, Q/K/V MFMA fragments are 16B-contiguous in global memory, so
// K and V are loaded STRAIGHT INTO REGISTERS (L1/L2 serve the cross-wave
// replication) -- no LDS staging, no glds, no double-buffer, and NO
// __syncthreads anywhere: the per-iteration vmcnt(0) barrier drain that
// capped every previous variant is gone.  Only the P strip round-trips
// through LDS (wave-private rows; same-wave RAW needs no barrier).
// ones-MFMA rowsum; truncation pack (bias cancels in P/sum(P)); Q pre-scaled
// at projection so exp is a bare v_exp_f32.  Grid q-fastest (L2 locality).
// ---------------------------------------------------------------------------
__global__ __launch_bounds__(256, 2) void attention(
    const ushort* __restrict__ qkv, const int* __restrict__ length,
    float* __restrict__ out)
{
    const int b = blockIdx.z, h = blockIdx.y, q0 = blockIdx.x * 128;
    int len = length[b];
    if (len > S_) len = S_;
    if (len < 1) len = 1;
    const int nkt = (len + 63) >> 6;

    const ushort* qb = qkv + ((size_t)(b * H_ + h) * S_ + q0) * DK_;
    const ushort* kb = qkv + (size_t)M_ * D_ + (size_t)(b * H_ + h) * S_ * DK_;
    const ushort* vb = qkv + (size_t)2 * M_ * D_ + (size_t)(b * H_ + h) * DK_ * S_;

    __shared__ __align__(16) ushort Ps[128 * 64];   // 16 KB, wave-private rows

    const int t = threadIdx.x, lane = t & 63, wid = t >> 6;
    const int quad = lane >> 4, l16 = lane & 15;
    const int e8 = (l16 & 7) << 1;   // even XOR phase for P rows (row&7==l16&7)

    // Q fragments straight from global: B-operand, lane=q-row, quad=dk-chunk
    short8 qfrag[2][2];
    #pragma unroll
    for (int st = 0; st < 2; ++st)
        #pragma unroll
        for (int ks = 0; ks < 2; ++ks) {
            const int q = wid * 32 + st * 16 + l16;
            qfrag[st][ks] =
                *(const short8*)(qb + (size_t)q * DK_ + (ks * 4 + quad) * 8);
        }

    short8 ones8;
    #pragma unroll
    for (int i = 0; i < 8; ++i) ones8[i] = (short)0x3F80;

    float4v cacc[2][4] = {};
    float4v racc[2] = {};

    for (int kt = 0; kt < nkt; ++kt) {
        // ---- S^T = K * Q^T : K A-frags straight from global --------------
        float4v sacc[2][4] = {};
        #pragma unroll
        for (int ks = 0; ks < 2; ++ks) {
            short8 kf[4];
            #pragma unroll
            for (int ct = 0; ct < 4; ++ct) {
                const int key = kt * 64 + ct * 16 + l16;
                kf[ct] = *(const short8*)(kb + (size_t)key * DK_ +
                                          (ks * 4 + quad) * 8);
            }
            #pragma unroll
            for (int ct = 0; ct < 4; ++ct)
                #pragma unroll
                for (int st = 0; st < 2; ++st)
                    sacc[st][ct] = __builtin_amdgcn_mfma_f32_16x16x32_bf16(
                        kf[ct], qfrag[st][ks], sacc[st][ct], 0, 0, 0);
        }

        // ---- exp2 + (boundary-only) mask + truncation-packed P write -----
        const bool full = ((kt + 1) * 64 <= len);
        #pragma unroll
        for (int st = 0; st < 2; ++st) {
            const int qrow = wid * 32 + st * 16 + l16;
            #pragma unroll
            for (int ct = 0; ct < 4; ++ct) {
                float v0 = __builtin_amdgcn_exp2f(sacc[st][ct][0]);
                float v1 = __builtin_amdgcn_exp2f(sacc[st][ct][1]);
                float v2 = __builtin_amdgcn_exp2f(sacc[st][ct][2]);
                float v3 = __builtin_amdgcn_exp2f(sacc[st][ct][3]);
                if (!full) {
                    const int kb0 = kt * 64 + ct * 16 + quad * 4;
                    v0 = (kb0 + 0 < len) ? v0 : 0.f;
                    v1 = (kb0 + 1 < len) ? v1 : 0.f;
                    v2 = (kb0 + 2 < len) ? v2 : 0.f;
                    v3 = (kb0 + 3 < len) ? v3 : 0.f;
                }
                uint2 w;
                w.x = (__float_as_uint(v0) >> 16) | (__float_as_uint(v1) & 0xFFFF0000u);
                w.y = (__float_as_uint(v2) >> 16) | (__float_as_uint(v3) & 0xFFFF0000u);
                const int c8 = (ct * 4 + quad) ^ e8;    // 8B-chunk swizzle
                *(uint2*)&Ps[qrow * 64 + c8 * 4] = w;
            }
        }

        // ---- P @ V + rowsum : V B-frags straight from global -------------
        #pragma unroll
        for (int ks = 0; ks < 2; ++ks) {
            short8 ap[2];
            #pragma unroll
            for (int st = 0; st < 2; ++st) {
                const int qrow = wid * 32 + st * 16 + l16;
                const int pp = ((ks * 4 + quad) * 2) ^ e8;   // even 8B chunk
                ap[st] = *(short8*)&Ps[qrow * 64 + pp * 4];
            }
            #pragma unroll
            for (int ct = 0; ct < 4; ++ct) {
                const int d = ct * 16 + l16;
                short8 vf = *(const short8*)(vb + (size_t)d * S_ + kt * 64 +
                                             (ks * 4 + quad) * 8);
                #pragma unroll
                for (int st = 0; st < 2; ++st)
                    cacc[st][ct] = __builtin_amdgcn_mfma_f32_16x16x32_bf16(
                        ap[st], vf, cacc[st][ct], 0, 0, 0);
            }
            #pragma unroll
            for (int st = 0; st < 2; ++st)
                racc[st] = __builtin_amdgcn_mfma_f32_16x16x32_bf16(
                    ap[st], ones8, racc[st], 0, 0, 0);
        }
    }

    // normalize + store fp32.  racc[st][rr] = rowsum for q = quad*4+rr of
    // strip st, in exactly the lane that holds cacc[st][ct][rr].
    #pragma unroll
    for (int st = 0; st < 2; ++st)
        #pragma unroll
        for (int rr = 0; rr < 4; ++rr) {
            const float inv = 1.0f / (racc[st][rr] + 1e-8f);
            const int q = q0 + wid * 32 + st * 16 + quad * 4 + rr;
            #pragma unroll
            for (int ct = 0; ct < 4; ++ct) {
                const int d = h * 64 + ct * 16 + l16;
                out[((size_t)b * S_ + q) * D_ + d] = cacc[st][ct][rr] * inv;
            }
        }
}

// ---------------------------------------------------------------------------
extern "C" void kernel_launch(void* const* d_in, const int* in_sizes, int n_in,
                              void* d_out, int out_size, void* d_ws, size_t ws_size,
                              hipStream_t stream)
{
    const float* Q   = (const float*)d_in[0];
    const int*   len = (const int*)d_in[1];
    const float* Wq  = (const float*)d_in[2];
    const float* bq  = (const float*)d_in[3];
    const float* Wk  = (const float*)d_in[4];
    const float* bk  = (const float*)d_in[5];
    const float* Wv  = (const float*)d_in[6];
    const float* bv  = (const float*)d_in[7];
    float* out = (float*)d_out;

    ushort* ws  = (ushort*)d_ws;
    ushort* Xb  = ws;                                   // 4M bf16 = 8 MB
    ushort* Wt  = ws + (size_t)M_ * D_;                 // 3M bf16 = 6 MB
    ushort* qkv = Wt + (size_t)3 * D_ * D_;             // 12M bf16 = 24 MB

    dim3 gPr(16, 16, 11);
    prep<<<gPr, 256, 0, stream>>>(Q, Wq, Wk, Wv, Xb, Wt);

    dim3 gP(M_ / 64, D_ / 128);
    proj_gemm<<<gP, 256, 0, stream>>>(Xb, Wt, bq, bk, bv, len, qkv);

    dim3 gA(S_ / 128, H_, B_);
    attention<<<gA, 256, 0, stream>>>(qkv, len, out);
}